// Round 6
// baseline (229.397 us; speedup 1.0000x reference)
//
#include <hip/hip_runtime.h>

constexpr float IMG_SIZE = 448.0f;
constexpr float GSZ = 64.0f;           // IMG_SIZE / GRID_NUM
constexpr float LAMBDA_COORD = 5.0f;
constexpr float LAMBDA_NOOBJ = 0.1f;
constexpr float EPSF = 1e-12f;

#define TPB 256          // threads per block (4 waves)
#define WPB 4            // waves per block
#define CPW 128          // cells per wave-tile (2 per lane)
#define MAXBLK 1280      // LDS 30.7 KB/block -> 5 blocks/CU * 256 CUs

// Zero-instruction intra-wave ordering fence: stops the compiler from
// reordering memory ops across it (the HW LDS pipe is in-order per wave,
// so compiler ordering is all we need for wave-private LDS tiles).
#define WAVE_FENCE() do { asm volatile("" ::: "memory"); \
                          __builtin_amdgcn_wave_barrier(); } while (0)

// Faithful port of reference _iou (including the y1_t = cy_t + w_t/2 typo).
// The grid-cell offset (gj*GSZ, gi*GSZ) is added to BOTH boxes identically and
// cancels in every max/min/difference -> IoU is translation-invariant, so the
// offsets are omitted (FP-rounding-level deviation only; threshold is 0.785).
__device__ __forceinline__ float iou_one(float b0, float b1, float b2, float b3,
                                         float tx, float ty, float tw, float th) {
    float cx_p = b0 * GSZ;
    float cy_p = b1 * GSZ;
    float w_p  = b2 * IMG_SIZE;
    float h_p  = b3 * IMG_SIZE;
    float x0p = cx_p - 0.5f * w_p, x1p = cx_p + 0.5f * w_p;
    float y0p = cy_p - 0.5f * h_p, y1p = cy_p + 0.5f * h_p;

    float cx_t = tx * GSZ;
    float cy_t = ty * GSZ;
    float w_t  = tw * IMG_SIZE;
    float h_t  = th * IMG_SIZE;
    float x0t = cx_t - 0.5f * w_t, x1t = cx_t + 0.5f * w_t;
    float y0t = cy_t - 0.5f * h_t;
    float y1t = cy_t + 0.5f * w_t;   // faithful typo: w_t, not h_t

    float ux0 = fmaxf(x0p, x0t), ux1 = fminf(x1p, x1t);
    float uy0 = fmaxf(y0p, y0t), uy1 = fminf(y1p, y1t);
    bool valid = (ux0 < ux1) && (uy0 < uy1);
    float au = (ux1 - ux0) * (uy1 - uy0);
    float ap = (x1p - x0p) * (y1p - y0p);
    float at = (x1t - x0t) * (y1t - y0t);
    float res = au / (ap + at - au + EPSF);
    return valid ? res : 0.0f;
}

__device__ __forceinline__ float cell_loss(float p0, float p1, float p2, float p3, float p4,
                                           float p5, float p6, float p7, float p8, float p9,
                                           float t0, float t1, float t2, float t3, float t4) {
    float iou0 = iou_one(p0, p1, p2, p3, t0, t1, t2, t3);
    float iou1 = iou_one(p5, p6, p7, p8, t0, t1, t2, t3);
    bool obj = (t4 == 1.0f);
    bool ch0 = iou0 > iou1;

    float cp = ch0 ? p4 : p9;
    float ct = ch0 ? iou0 : iou1;
    float d  = cp - ct;
    float loss_obj = d * d;
    float dx = (ch0 ? p0 : p5) - t0;
    float dy = (ch0 ? p1 : p6) - t1;
    loss_obj += LAMBDA_COORD * (dx * dx + dy * dy);
    float wp = fmaxf(ch0 ? p2 : p7, EPSF);
    float hp = fmaxf(ch0 ? p3 : p8, EPSF);
    float wt = fmaxf(t2, EPSF);
    float ht = fmaxf(t3, EPSF);
    float dw = sqrtf(wp) - sqrtf(wt);
    float dh = sqrtf(hp) - sqrtf(ht);
    loss_obj += LAMBDA_COORD * (dw * dw + dh * dh);

    float loss_noobj = LAMBDA_NOOBJ * (p4 * p4 + p9 * p9);
    return obj ? loss_obj : loss_noobj;
}

// Barrier-free wave-pipelined main kernel:
//   per iteration: ds_write(tile t regs) | FENCE | issue loads(t+W) |
//                  compute(t from LDS)   | FENCE
// Wave-private LDS tile => no __syncthreads in the loop => no vmcnt(0)
// barrier drain; each wave keeps its next tile's global loads in flight
// across its entire compute phase.
__global__ __launch_bounds__(TPB)
void yolo_loss_kernel(const float* __restrict__ y_pre,
                      const float* __restrict__ y_true,
                      float* __restrict__ partials,
                      int ntiles) {
    __shared__ float4 sp4[WPB][CPW * 10 / 4];   // 20480 B
    __shared__ float4 st4[WPB][CPW * 5 / 4];    // 10240 B

    const int tid  = threadIdx.x;
    const int lane = tid & 63;
    const int wid  = tid >> 6;
    const int gw   = blockIdx.x * WPB + wid;    // global wave id
    const int W    = gridDim.x * WPB;

    float4* spw = sp4[wid];
    float4* stw = st4[wid];
    const float* spf = (const float*)spw;
    const float* stf = (const float*)stw;

    float4 rp0, rp1, rp2, rp3, rp4;             // y_pre tile: 320 float4, 5/lane
    float4 rt0, rt1;                            // y_true tile: 128 float4, 2/lane
    float2 rt2;                                 //   + last 512 B as float2/lane

    float acc = 0.0f;

    if (gw < ntiles) {                          // prologue: first tile -> regs
        const float4* pb = (const float4*)(y_pre + (size_t)gw * (CPW * 10));
        const float4* tb = (const float4*)(y_true + (size_t)gw * (CPW * 5));
        rp0 = pb[lane];        rp1 = pb[lane + 64];  rp2 = pb[lane + 128];
        rp3 = pb[lane + 192];  rp4 = pb[lane + 256];
        rt0 = tb[lane];        rt1 = tb[lane + 64];
        rt2 = ((const float2*)tb)[256 + lane];
    }

    for (int t = gw; t < ntiles; t += W) {
        // 1) Commit tile t regs -> wave-private LDS (compiler inserts the
        //    vmcnt wait; the loads had a full compute phase to land).
        spw[lane]       = rp0;  spw[lane + 64]  = rp1;  spw[lane + 128] = rp2;
        spw[lane + 192] = rp3;  spw[lane + 256] = rp4;
        stw[lane]       = rt0;  stw[lane + 64]  = rt1;
        ((float2*)stw)[256 + lane] = rt2;

        // Cross-lane LDS dependency: reads below consume other lanes' writes.
        // HW DS pipe is in-order per wave; this fence stops compiler reorder.
        WAVE_FENCE();

        // 2) Issue tile t+W's global loads (hidden behind compute below).
        int tn = t + W;
        if (tn < ntiles) {
            const float4* pb = (const float4*)(y_pre + (size_t)tn * (CPW * 10));
            const float4* tb = (const float4*)(y_true + (size_t)tn * (CPW * 5));
            rp0 = pb[lane];        rp1 = pb[lane + 64];  rp2 = pb[lane + 128];
            rp3 = pb[lane + 192];  rp4 = pb[lane + 256];
            rt0 = tb[lane];        rt1 = tb[lane + 64];
            rt2 = ((const float2*)tb)[256 + lane];
        }

        // 3) Compute tile t from LDS.
        #pragma unroll
        for (int k = 0; k < 2; ++k) {
            int ci = lane + 64 * k;
            const float* p = spf + ci * 10;
            const float* u = stf + ci * 5;
            acc += cell_loss(p[0], p[1], p[2], p[3], p[4],
                             p[5], p[6], p[7], p[8], p[9],
                             u[0], u[1], u[2], u[3], u[4]);
        }

        // WAR: next iteration's ds_writes must not move above these reads.
        WAVE_FENCE();
    }

    // Block reduction: wave shuffle -> LDS -> one plain store per block.
    #pragma unroll
    for (int off = 32; off > 0; off >>= 1)
        acc += __shfl_down(acc, off, 64);

    __shared__ float smem[WPB];
    if (lane == 0) smem[wid] = acc;
    __syncthreads();
    if (tid == 0) {
        float s = 0.0f;
        #pragma unroll
        for (int w = 0; w < WPB; ++w) s += smem[w];
        partials[blockIdx.x] = s;
    }
}

__global__ __launch_bounds__(TPB)
void reduce_kernel(const float* __restrict__ partials, int nparts,
                   const float* __restrict__ y_pre,
                   const float* __restrict__ y_true,
                   int tail_start, int cells,
                   float* __restrict__ out, float invB) {
    int tid = threadIdx.x;
    float s = 0.0f;
    for (int i = tid; i < nparts; i += TPB) s += partials[i];
    // Tail cells not covered by full wave-tiles (0 for this shape).
    for (int c = tail_start + tid; c < cells; c += TPB) {
        const float* p = y_pre + (size_t)c * 10;
        const float* u = y_true + (size_t)c * 5;
        s += cell_loss(p[0], p[1], p[2], p[3], p[4],
                       p[5], p[6], p[7], p[8], p[9],
                       u[0], u[1], u[2], u[3], u[4]);
    }

    #pragma unroll
    for (int off = 32; off > 0; off >>= 1)
        s += __shfl_down(s, off, 64);

    __shared__ float smem[TPB / 64];
    int lane = tid & 63;
    int wid  = tid >> 6;
    if (lane == 0) smem[wid] = s;
    __syncthreads();
    if (tid == 0) {
        float tot = 0.0f;
        #pragma unroll
        for (int w = 0; w < TPB / 64; ++w) tot += smem[w];
        out[0] = tot * invB;
    }
}

extern "C" void kernel_launch(void* const* d_in, const int* in_sizes, int n_in,
                              void* d_out, int out_size, void* d_ws, size_t ws_size,
                              hipStream_t stream) {
    const float* y_pre  = (const float*)d_in[0];
    const float* y_true = (const float*)d_in[1];
    float* out = (float*)d_out;
    float* partials = (float*)d_ws;

    int cells = in_sizes[0] / 10;            // B * 7 * 7
    int B     = cells / 49;
    float invB = 1.0f / (float)B;

    int ntiles = cells / CPW;                // full wave-tiles
    int nblocks = (ntiles + WPB - 1) / WPB;
    if (nblocks > MAXBLK) nblocks = MAXBLK;
    if (nblocks < 1) nblocks = 1;

    yolo_loss_kernel<<<nblocks, TPB, 0, stream>>>(y_pre, y_true, partials, ntiles);
    reduce_kernel<<<1, TPB, 0, stream>>>(partials, nblocks, y_pre, y_true,
                                         ntiles * CPW, cells, out, invB);
}